// Round 17
// baseline (47.439 us; speedup 1.0000x reference)
//
#include <hip/hip_runtime.h>
#include <math.h>

#define B_   512
#define W_   30
#define R_   512
#define D_   128
#define NK_  21

typedef __attribute__((ext_vector_type(8))) short  bf16x8;
typedef __attribute__((ext_vector_type(4))) float  f32x4;
typedef __attribute__((ext_vector_type(2))) float  f32x2;

__device__ __forceinline__ unsigned short f2bf(float f) {
    union { float f; unsigned int u; } v; v.f = f;
    unsigned int u = v.u;
    return (unsigned short)((u + 0x7fffu + ((u >> 16) & 1u)) >> 16);  // RTNE
}

__device__ __forceinline__ float fast_exp2(float x) {
#if __has_builtin(__builtin_amdgcn_exp2f)
    return __builtin_amdgcn_exp2f(x);
#else
    float r; asm volatile("v_exp_f32 %0, %1" : "=v"(r) : "v"(x)); return r;
#endif
}

#define QROWS 32
#define QST   136   // ushort stride per row (272 B)

__device__ __forceinline__ void bins_accum(f32x4 acc0, f32x4 acc1, int l15, f32x2* kacc2)
{
    const float CW = -72.134752f;     // -0.5/0.1^2 * log2(e)
    const float CE = -721347.52f;     // exact bin, sigma=0.001
    const float RC = 0.36787944f;     // 2^(2*CW*0.01) = e^-1

    #pragma unroll
    for (int p = 0; p < 4; ++p) {
        f32x2 mm;
        mm.x = acc0[p];                              // w = l15 (always valid)
        mm.y = (l15 < 14) ? acc1[p] : -3.0f;         // w = 16+l15, mask w>=30 -> all terms 0
        f32x2 t0 = mm + 0.95f;                       // m - mu0, mu0 = -0.95

        #pragma unroll
        for (int g = 0; g < 3; ++g) {
            const int   gs = (g == 0) ? 0 : (g == 1) ? 7 : 14;
            const int   gl = (g == 2) ? 6 : 7;
            const float go = 0.1f * (float)gs;
            f32x2 tg = t0 - go;
            f32x2 e  = (CW * tg) * tg;
            f32x2 dl = 14.4269504f * tg - 0.72134752f;   // -2*CW*0.1*tg + CW*0.01
            f32x2 R, r;
            R.x = fast_exp2(e.x);  R.y = fast_exp2(e.y);
            r.x = fast_exp2(dl.x); r.y = fast_exp2(dl.y);
            #pragma unroll
            for (int k = 0; k < 7; ++k) {
                if (k < gl) {
                    kacc2[gs + k] += R;
                    R *= r;
                    r *= RC;
                }
            }
        }

        // bin 20 (sigma=0.001): zero unless m > 0.98 (else exp2 < 2^-288).
        if (__any(mm.x > 0.98f || mm.y > 0.98f)) {
            f32x2 y = mm - 1.0f;
            f32x2 a20 = (CE * y) * y;
            f32x2 T20;
            T20.x = fast_exp2(a20.x);
            T20.y = fast_exp2(a20.y);
            kacc2[20] += T20;
        }
    }
}

// ---------------- fused kernel: bins (4 pipelined groups/wave) + log1p + MLP ----------------
__global__ __launch_bounds__(512) void knrm_fused_kernel(
    const int* __restrict__ query, const int* __restrict__ doc,
    const float* __restrict__ emb,            // [V][128] raw fp32
    const float* __restrict__ w1, const float* __restrict__ b1,
    const float* __restrict__ w2, const float* __restrict__ b2,
    const float* __restrict__ w3, const float* __restrict__ b3,
    float* __restrict__ out)
{
    const int b    = blockIdx.x;
    const int tid  = threadIdx.x;
    const int lane = tid & 63;
    const int wid  = tid >> 6;          // 8 waves, 64 doc rows each
    const int l15  = lane & 15;
    const int lhi  = lane >> 4;

    __shared__ unsigned short qlds[QROWS * QST];
    __shared__ float wred8[8][NK_][8];   // wave, bin, 8-lane class
    __shared__ float klds[NK_];
    __shared__ float h1lds[128];

    // ---- this wave's 64 doc rows: 4 groups of 16 ----
    int di[4];
    #pragma unroll
    for (int g = 0; g < 4; ++g)
        di[g] = doc[b * R_ + wid * 64 + g * 16 + l15];

    // ---- G0 loads (in flight across q-staging + barrier) ----
    const float* dr0 = emb + (size_t)di[0] * D_ + lhi * 8;
    float4 f[8];
    #pragma unroll
    for (int kk = 0; kk < 4; ++kk) {
        f[2 * kk]     = *(const float4*)(dr0 + kk * 32);
        f[2 * kk + 1] = *(const float4*)(dr0 + kk * 32 + 4);
    }

    // ---- q rows: load fp32, normalize, store bf16 to LDS; pad rows 30,31 with 0 ----
    {
        int w = tid >> 4, j = tid & 15;          // 32 rows x 16 threads
        uint4 o4 = make_uint4(0, 0, 0, 0);
        if (w < W_) {
            int qi = query[b * W_ + w];
            const float* qrow = emb + (size_t)qi * D_ + j * 8;
            float4 qa = *(const float4*)(qrow);
            float4 qb = *(const float4*)(qrow + 4);
            float ss = qa.x*qa.x + qa.y*qa.y + qa.z*qa.z + qa.w*qa.w
                     + qb.x*qb.x + qb.y*qb.y + qb.z*qb.z + qb.w*qb.w;
            #pragma unroll
            for (int off = 8; off >= 1; off >>= 1) ss += __shfl_xor(ss, off, 16);
            float qinv = 1.0f / fmaxf(sqrtf(ss), 1e-12f);
            unsigned short o[8];
            o[0] = f2bf(qa.x*qinv); o[1] = f2bf(qa.y*qinv);
            o[2] = f2bf(qa.z*qinv); o[3] = f2bf(qa.w*qinv);
            o[4] = f2bf(qb.x*qinv); o[5] = f2bf(qb.y*qinv);
            o[6] = f2bf(qb.z*qinv); o[7] = f2bf(qb.w*qinv);
            o4 = *(const uint4*)o;
        }
        *(uint4*)(&qlds[(tid >> 4) * QST + (tid & 15) * 8]) = o4;
    }
    __syncthreads();

    f32x2 kacc2[NK_];
    #pragma unroll
    for (int i = 0; i < NK_; ++i) kacc2[i] = (f32x2)0.0f;

    // ---- 4 pipelined groups: convert(g) -> issue loads(g+1) -> MFMA+bins(g) ----
    #pragma unroll
    for (int g = 0; g < 4; ++g) {
        // norm reduce across the 4 lanes sharing a row
        float nsq = 0.f;
        #pragma unroll
        for (int c = 0; c < 8; ++c)
            nsq = fmaf(f[c].x, f[c].x, fmaf(f[c].y, f[c].y,
                  fmaf(f[c].z, f[c].z, fmaf(f[c].w, f[c].w, nsq))));
        nsq += __shfl_xor(nsq, 16, 64);
        nsq += __shfl_xor(nsq, 32, 64);
        const float dinv = 1.0f / fmaxf(sqrtf(nsq), 1e-12f);

        bf16x8 a[4];
        #pragma unroll
        for (int kk = 0; kk < 4; ++kk) {
            float4 u = f[2 * kk], v = f[2 * kk + 1];
            unsigned short o[8];
            o[0] = f2bf(u.x*dinv); o[1] = f2bf(u.y*dinv);
            o[2] = f2bf(u.z*dinv); o[3] = f2bf(u.w*dinv);
            o[4] = f2bf(v.x*dinv); o[5] = f2bf(v.y*dinv);
            o[6] = f2bf(v.z*dinv); o[7] = f2bf(v.w*dinv);
            a[kk] = *(const bf16x8*)o;
        }

        // issue next group's loads; latency hides under this group's MFMA+bins
        if (g < 3) {
            const float* drn = emb + (size_t)di[g + 1] * D_ + lhi * 8;
            #pragma unroll
            for (int kk = 0; kk < 4; ++kk) {
                f[2 * kk]     = *(const float4*)(drn + kk * 32);
                f[2 * kk + 1] = *(const float4*)(drn + kk * 32 + 4);
            }
        }

        // MFMA (bq read fresh from LDS -> not live through bins)
        f32x4 acc0 = (f32x4)0.0f, acc1 = (f32x4)0.0f;
        #pragma unroll
        for (int kk = 0; kk < 4; ++kk) {
            bf16x8 b0 = *(const bf16x8*)&qlds[(l15)      * QST + kk * 32 + lhi * 8];
            bf16x8 b1 = *(const bf16x8*)&qlds[(16 + l15) * QST + kk * 32 + lhi * 8];
            acc0 = __builtin_amdgcn_mfma_f32_16x16x32_bf16(a[kk], b0, acc0, 0, 0, 0);
            acc1 = __builtin_amdgcn_mfma_f32_16x16x32_bf16(a[kk], b1, acc1, 0, 0, 0);
        }
        bins_accum(acc0, acc1, l15, kacc2);
    }

    // ---- reduction: pair-sum, 3-level shfl (8-lane classes), LDS stripe ----
    #pragma unroll
    for (int i = 0; i < NK_; ++i) {
        float v = kacc2[i].x + kacc2[i].y;
        v += __shfl_xor(v, 8, 64);
        v += __shfl_xor(v, 16, 64);
        v += __shfl_xor(v, 32, 64);
        if (lane < 8) wred8[wid][i][lane] = v;
    }
    __syncthreads();
    if (tid < NK_) {
        float s = 0.f;
        #pragma unroll
        for (int ww = 0; ww < 8; ++ww)
            #pragma unroll
            for (int c = 0; c < 8; ++c) s += wred8[ww][tid][c];
        klds[tid] = log1pf(s);
    }
    __syncthreads();

    // ---- fused MLP tail: 21 -> 128 -> 64 -> 1 (identical to verified r5 tail) ----
    if (tid < 128) {
        float h = b1[tid];
        #pragma unroll
        for (int i = 0; i < NK_; ++i) h = fmaf(klds[i], w1[i * 128 + tid], h);
        h1lds[tid] = fmaxf(h, 0.f);
    }
    __syncthreads();
    if (tid < 64) {
        float h = b2[tid];
        #pragma unroll 8
        for (int i = 0; i < 128; ++i) h = fmaf(h1lds[i], w2[i * 64 + tid], h);
        float p = fmaxf(h, 0.f) * w3[tid];
        #pragma unroll
        for (int off = 32; off >= 1; off >>= 1) p += __shfl_xor(p, off, 64);
        if (tid == 0) out[b] = p + b3[0];
    }
}

extern "C" void kernel_launch(void* const* d_in, const int* in_sizes, int n_in,
                              void* d_out, int out_size, void* d_ws, size_t ws_size,
                              hipStream_t stream) {
    const int*   query = (const int*)d_in[0];
    const int*   doc   = (const int*)d_in[1];
    const float* emb   = (const float*)d_in[2];
    const float* w1    = (const float*)d_in[3];
    const float* b1    = (const float*)d_in[4];
    const float* w2    = (const float*)d_in[5];
    const float* b2    = (const float*)d_in[6];
    const float* w3    = (const float*)d_in[7];
    const float* b3    = (const float*)d_in[8];
    float* outp = (float*)d_out;

    knrm_fused_kernel<<<dim3(B_), dim3(512), 0, stream>>>(query, doc, emb,
                                                          w1, b1, w2, b2, w3, b3, outp);
}

// Round 19
// 42.221 us; speedup vs baseline: 1.1236x; 1.1236x over previous
//
#include <hip/hip_runtime.h>
#include <math.h>

#define B_   512
#define W_   30
#define R_   512
#define D_   128
#define NK_  21
#define SPLIT 2       // blocks per batch in the bins kernel
#define QSTRIDE 132   // fp32 fallback kernel: 128 + 4 pad

typedef __attribute__((ext_vector_type(8))) short  bf16x8;
typedef __attribute__((ext_vector_type(4))) float  f32x4;
typedef __attribute__((ext_vector_type(2))) float  f32x2;

__device__ __forceinline__ unsigned short f2bf(float f) {
    union { float f; unsigned int u; } v; v.f = f;
    unsigned int u = v.u;
    return (unsigned short)((u + 0x7fffu + ((u >> 16) & 1u)) >> 16);  // RTNE
}

__device__ __forceinline__ float fast_exp2(float x) {
#if __has_builtin(__builtin_amdgcn_exp2f)
    return __builtin_amdgcn_exp2f(x);
#else
    float r; asm volatile("v_exp_f32 %0, %1" : "=v"(r) : "v"(x)); return r;
#endif
}

// ---------------- kernel: partial bin sums, inline norm, 2 groups/wave ----------------
#define QROWS 32
#define QST   136   // ushort stride per row (272 B)

__device__ __forceinline__ void bins_accum(f32x4 acc0, f32x4 acc1, int l15, f32x2* kacc2)
{
    const float CW = -72.134752f;     // -0.5/0.1^2 * log2(e)
    const float CE = -721347.52f;     // exact bin, sigma=0.001
    const float RC = 0.36787944f;     // 2^(2*CW*0.01) = e^-1

    #pragma unroll
    for (int p = 0; p < 4; ++p) {
        f32x2 mm;
        mm.x = acc0[p];                              // w = l15 (always valid)
        mm.y = (l15 < 14) ? acc1[p] : -3.0f;         // w = 16+l15, mask w>=30 -> all terms 0
        f32x2 t0 = mm + 0.95f;                       // m - mu0, mu0 = -0.95

        #pragma unroll
        for (int g = 0; g < 3; ++g) {
            const int   gs = (g == 0) ? 0 : (g == 1) ? 7 : 14;
            const int   gl = (g == 2) ? 6 : 7;
            const float go = 0.1f * (float)gs;
            f32x2 tg = t0 - go;
            f32x2 e  = (CW * tg) * tg;
            f32x2 dl = 14.4269504f * tg - 0.72134752f;   // -2*CW*0.1*tg + CW*0.01
            f32x2 R, r;
            R.x = fast_exp2(e.x);  R.y = fast_exp2(e.y);
            r.x = fast_exp2(dl.x); r.y = fast_exp2(dl.y);
            #pragma unroll
            for (int k = 0; k < 7; ++k) {
                if (k < gl) {
                    kacc2[gs + k] += R;
                    R *= r;
                    r *= RC;
                }
            }
        }

        // bin 20 (sigma=0.001): zero unless m > 0.98 (else exp2 < 2^-288).
        // Wave-uniform rare branch; sentinel -3.0 never triggers it.
        if (__any(mm.x > 0.98f || mm.y > 0.98f)) {
            f32x2 y = mm - 1.0f;
            f32x2 a20 = (CE * y) * y;
            f32x2 T20;
            T20.x = fast_exp2(a20.x);
            T20.y = fast_exp2(a20.y);
            kacc2[20] += T20;
        }
    }
}

__global__ __launch_bounds__(512) void knrm_bins_kernel(
    const int* __restrict__ query, const int* __restrict__ doc,
    const float* __restrict__ emb,            // [V][128] raw fp32
    float* __restrict__ part)                 // [B*SPLIT][21], logical (b,sp) order
{
    // XCD batch-cohesion swizzle: batch b's 2 split blocks share XCD (b&7)
    // grid g = ((b>>3)*2 + sp)*8 + (b&7); 1024 % 8 == 0 -> bijective
    const int bid  = blockIdx.x;
    const int b    = ((bid >> 4) << 3) | (bid & 7);
    const int sp   = (bid >> 3) & 1;
    const int tid  = threadIdx.x;
    const int lane = tid & 63;
    const int wid  = tid >> 6;          // 8 waves
    const int l15  = lane & 15;
    const int lhi  = lane >> 4;

    __shared__ unsigned short qlds[QROWS * QST];
    __shared__ float wred8[8][NK_][8];   // wave, bin, 8-lane class

    // ---- wave owns 32 doc rows: two 16-row groups ----
    const int rbase = sp * 256 + wid * 32 + l15;
    const int di0 = doc[b * R_ + rbase];
    const int di1 = doc[b * R_ + rbase + 16];

    // ---- G0 loads (in flight across q-staging + barrier) ----
    const float* dr0 = emb + (size_t)di0 * D_ + lhi * 8;
    float4 f[8];
    #pragma unroll
    for (int kk = 0; kk < 4; ++kk) {
        f[2 * kk]     = *(const float4*)(dr0 + kk * 32);
        f[2 * kk + 1] = *(const float4*)(dr0 + kk * 32 + 4);
    }

    // ---- q rows: load fp32, normalize, store bf16 to LDS; pad rows 30,31 with 0 ----
    {
        int w = tid >> 4, j = tid & 15;          // 32 rows x 16 threads
        uint4 o4 = make_uint4(0, 0, 0, 0);
        if (w < W_) {
            int qi = query[b * W_ + w];
            const float* qrow = emb + (size_t)qi * D_ + j * 8;
            float4 qa = *(const float4*)(qrow);
            float4 qb = *(const float4*)(qrow + 4);
            float ss = qa.x*qa.x + qa.y*qa.y + qa.z*qa.z + qa.w*qa.w
                     + qb.x*qb.x + qb.y*qb.y + qb.z*qb.z + qb.w*qb.w;
            #pragma unroll
            for (int off = 8; off >= 1; off >>= 1) ss += __shfl_xor(ss, off, 16);
            float qinv = 1.0f / fmaxf(sqrtf(ss), 1e-12f);
            unsigned short o[8];
            o[0] = f2bf(qa.x*qinv); o[1] = f2bf(qa.y*qinv);
            o[2] = f2bf(qa.z*qinv); o[3] = f2bf(qa.w*qinv);
            o[4] = f2bf(qb.x*qinv); o[5] = f2bf(qb.y*qinv);
            o[6] = f2bf(qb.z*qinv); o[7] = f2bf(qb.w*qinv);
            o4 = *(const uint4*)o;
        }
        *(uint4*)(&qlds[(tid >> 4) * QST + (tid & 15) * 8]) = o4;
    }
    __syncthreads();

    f32x2 kacc2[NK_];
    #pragma unroll
    for (int i = 0; i < NK_; ++i) kacc2[i] = (f32x2)0.0f;

    // ================= group 0 =================
    float nsq = 0.f;
    #pragma unroll
    for (int c = 0; c < 8; ++c)
        nsq = fmaf(f[c].x, f[c].x, fmaf(f[c].y, f[c].y,
              fmaf(f[c].z, f[c].z, fmaf(f[c].w, f[c].w, nsq))));
    nsq += __shfl_xor(nsq, 16, 64);
    nsq += __shfl_xor(nsq, 32, 64);
    float dinv = 1.0f / fmaxf(sqrtf(nsq), 1e-12f);

    bf16x8 a[4];
    #pragma unroll
    for (int kk = 0; kk < 4; ++kk) {
        float4 u = f[2 * kk], v = f[2 * kk + 1];
        unsigned short o[8];
        o[0] = f2bf(u.x*dinv); o[1] = f2bf(u.y*dinv);
        o[2] = f2bf(u.z*dinv); o[3] = f2bf(u.w*dinv);
        o[4] = f2bf(v.x*dinv); o[5] = f2bf(v.y*dinv);
        o[6] = f2bf(v.z*dinv); o[7] = f2bf(v.w*dinv);
        a[kk] = *(const bf16x8*)o;
    }

    // ---- G1 loads: reuse f[], fly during G0 MFMA+bins ----
    const float* dr1 = emb + (size_t)di1 * D_ + lhi * 8;
    #pragma unroll
    for (int kk = 0; kk < 4; ++kk) {
        f[2 * kk]     = *(const float4*)(dr1 + kk * 32);
        f[2 * kk + 1] = *(const float4*)(dr1 + kk * 32 + 4);
    }

    {   // MFMA G0 (bq read fresh from LDS -> not live through bins)
        f32x4 acc0 = (f32x4)0.0f, acc1 = (f32x4)0.0f;
        #pragma unroll
        for (int kk = 0; kk < 4; ++kk) {
            bf16x8 b0 = *(const bf16x8*)&qlds[(l15)      * QST + kk * 32 + lhi * 8];
            bf16x8 b1 = *(const bf16x8*)&qlds[(16 + l15) * QST + kk * 32 + lhi * 8];
            acc0 = __builtin_amdgcn_mfma_f32_16x16x32_bf16(a[kk], b0, acc0, 0, 0, 0);
            acc1 = __builtin_amdgcn_mfma_f32_16x16x32_bf16(a[kk], b1, acc1, 0, 0, 0);
        }
        bins_accum(acc0, acc1, l15, kacc2);
    }

    // ================= group 1 =================
    nsq = 0.f;
    #pragma unroll
    for (int c = 0; c < 8; ++c)
        nsq = fmaf(f[c].x, f[c].x, fmaf(f[c].y, f[c].y,
              fmaf(f[c].z, f[c].z, fmaf(f[c].w, f[c].w, nsq))));
    nsq += __shfl_xor(nsq, 16, 64);
    nsq += __shfl_xor(nsq, 32, 64);
    dinv = 1.0f / fmaxf(sqrtf(nsq), 1e-12f);

    #pragma unroll
    for (int kk = 0; kk < 4; ++kk) {
        float4 u = f[2 * kk], v = f[2 * kk + 1];
        unsigned short o[8];
        o[0] = f2bf(u.x*dinv); o[1] = f2bf(u.y*dinv);
        o[2] = f2bf(u.z*dinv); o[3] = f2bf(u.w*dinv);
        o[4] = f2bf(v.x*dinv); o[5] = f2bf(v.y*dinv);
        o[6] = f2bf(v.z*dinv); o[7] = f2bf(v.w*dinv);
        a[kk] = *(const bf16x8*)o;
    }

    {   // MFMA G1
        f32x4 acc0 = (f32x4)0.0f, acc1 = (f32x4)0.0f;
        #pragma unroll
        for (int kk = 0; kk < 4; ++kk) {
            bf16x8 b0 = *(const bf16x8*)&qlds[(l15)      * QST + kk * 32 + lhi * 8];
            bf16x8 b1 = *(const bf16x8*)&qlds[(16 + l15) * QST + kk * 32 + lhi * 8];
            acc0 = __builtin_amdgcn_mfma_f32_16x16x32_bf16(a[kk], b0, acc0, 0, 0, 0);
            acc1 = __builtin_amdgcn_mfma_f32_16x16x32_bf16(a[kk], b1, acc1, 0, 0, 0);
        }
        bins_accum(acc0, acc1, l15, kacc2);
    }

    // ---- reduction: pair-sum, 3-level shfl (8-lane classes), LDS stripe ----
    #pragma unroll
    for (int i = 0; i < NK_; ++i) {
        float v = kacc2[i].x + kacc2[i].y;
        v += __shfl_xor(v, 8, 64);
        v += __shfl_xor(v, 16, 64);
        v += __shfl_xor(v, 32, 64);
        if (lane < 8) wred8[wid][i][lane] = v;
    }
    __syncthreads();
    if (tid < NK_) {
        float s = 0.f;
        #pragma unroll
        for (int ww = 0; ww < 8; ++ww)
            #pragma unroll
            for (int c = 0; c < 8; ++c) s += wred8[ww][tid][c];
        part[(b * SPLIT + sp) * NK_ + tid] = s;
    }
}

// ---------------- kernel: sum partials + log1p + MLP 21->128->64->1 ----------------
__global__ __launch_bounds__(128) void knrm_mlp_kernel(
    const float* __restrict__ part,
    const float* __restrict__ w1, const float* __restrict__ b1,
    const float* __restrict__ w2, const float* __restrict__ b2,
    const float* __restrict__ w3, const float* __restrict__ b3,
    float* __restrict__ out)
{
    const int b   = blockIdx.x;
    const int tid = threadIdx.x;

    __shared__ float klds[NK_];
    __shared__ float h1lds[128];

    if (tid < NK_) {
        const float* p0 = part + (size_t)b * SPLIT * NK_;
        float s = p0[tid] + p0[NK_ + tid];
        klds[tid] = log1pf(s);
    }
    __syncthreads();

    {
        float h = b1[tid];
        #pragma unroll
        for (int i = 0; i < NK_; ++i) h = fmaf(klds[i], w1[i * 128 + tid], h);
        h1lds[tid] = fmaxf(h, 0.f);
    }
    __syncthreads();

    if (tid < 64) {
        float h = b2[tid];
        #pragma unroll 8
        for (int i = 0; i < 128; ++i) h = fmaf(h1lds[i], w2[i * 64 + tid], h);
        float p = fmaxf(h, 0.f) * w3[tid];
        #pragma unroll
        for (int off = 32; off >= 1; off >>= 1) p += __shfl_xor(p, off, 64);
        if (tid == 0) out[b] = p + b3[0];
    }
}

// ---------------- fp32 fallback (round-5 kernel, exact) ----------------
__global__ __launch_bounds__(512) void knrm_kernel(
    const int* __restrict__ query, const int* __restrict__ doc,
    const float* __restrict__ emb,
    const float* __restrict__ w1, const float* __restrict__ b1,
    const float* __restrict__ w2, const float* __restrict__ b2,
    const float* __restrict__ w3, const float* __restrict__ b3,
    float* __restrict__ out)
{
    const int b   = blockIdx.x;
    const int tid = threadIdx.x;

    __shared__ float qs[W_ * QSTRIDE];
    __shared__ float qinv[W_];
    __shared__ float wred[8][NK_];
    __shared__ float klds[NK_];
    __shared__ float h1lds[128];

    for (int idx = tid; idx < W_ * D_; idx += 512) {
        int w = idx >> 7, k = idx & 127;
        int qi = query[b * W_ + w];
        qs[w * QSTRIDE + k] = emb[(size_t)qi * D_ + k];
    }
    __syncthreads();

    if (tid < W_ * 16) {
        int row = tid >> 4, j = tid & 15;
        float ss = 0.f;
        #pragma unroll
        for (int k = 0; k < D_; k += 16) {
            float v = qs[row * QSTRIDE + k + j];
            ss = fmaf(v, v, ss);
        }
        #pragma unroll
        for (int off = 8; off >= 1; off >>= 1) ss += __shfl_xor(ss, off, 16);
        if (j == 0) qinv[row] = 1.0f / fmaxf(sqrtf(ss), 1e-12f);
    }
    __syncthreads();

    const int didx = doc[b * R_ + tid];
    const float4* __restrict__ drow = (const float4*)(emb + (size_t)didx * D_);

    float acc[W_];
    #pragma unroll
    for (int w = 0; w < W_; ++w) acc[w] = 0.f;
    float nsq = 0.f;

    float4 dv = drow[0];
    for (int c = 0; c < D_ / 4; ++c) {
        float4 dnx = drow[(c + 1) & 31];
        nsq = fmaf(dv.x, dv.x, fmaf(dv.y, dv.y, fmaf(dv.z, dv.z, fmaf(dv.w, dv.w, nsq))));
        const float* qc = qs + c * 4;
        #pragma unroll
        for (int w = 0; w < W_; ++w) {
            float4 qv = *(const float4*)(qc + w * QSTRIDE);
            acc[w] = fmaf(qv.x, dv.x, fmaf(qv.y, dv.y, fmaf(qv.z, dv.z, fmaf(qv.w, dv.w, acc[w]))));
        }
        dv = dnx;
    }
    const float invd = 1.0f / fmaxf(sqrtf(nsq), 1e-12f);

    const float CW = -72.134752f;
    const float CE = -721347.52f;
    float kacc[NK_];
    #pragma unroll
    for (int i = 0; i < NK_; ++i) kacc[i] = 0.f;

    #pragma unroll
    for (int w = 0; w < W_; ++w) {
        float m = acc[w] * qinv[w] * invd;
        #pragma unroll
        for (int i = 0; i < 20; ++i) {
            const float mu = (float)(1.0 / (NK_ - 1) + 2.0 * (double)i / (NK_ - 1) - 1.0);
            float t = m - mu;
            kacc[i] += exp2f(CW * t * t);
        }
        float y = m - 1.0f;
        kacc[20] += exp2f(CE * y * y);
    }

    const int wid = tid >> 6, lane = tid & 63;
    #pragma unroll
    for (int i = 0; i < NK_; ++i) {
        float v = kacc[i];
        #pragma unroll
        for (int off = 32; off >= 1; off >>= 1) v += __shfl_xor(v, off, 64);
        if (lane == 0) wred[wid][i] = v;
    }
    __syncthreads();
    if (tid < NK_) {
        float s = 0.f;
        #pragma unroll
        for (int ww = 0; ww < 8; ++ww) s += wred[ww][tid];
        klds[tid] = log1pf(s);
    }
    __syncthreads();

    if (tid < 128) {
        float h = b1[tid];
        #pragma unroll
        for (int i = 0; i < NK_; ++i) h = fmaf(klds[i], w1[i * 128 + tid], h);
        h1lds[tid] = fmaxf(h, 0.f);
    }
    __syncthreads();
    if (tid < 64) {
        float h = b2[tid];
        #pragma unroll 8
        for (int i = 0; i < 128; ++i) h = fmaf(h1lds[i], w2[i * 64 + tid], h);
        float p = fmaxf(h, 0.f) * w3[tid];
        #pragma unroll
        for (int off = 32; off >= 1; off >>= 1) p += __shfl_xor(p, off, 64);
        if (tid == 0) out[b] = p + b3[0];
    }
}

extern "C" void kernel_launch(void* const* d_in, const int* in_sizes, int n_in,
                              void* d_out, int out_size, void* d_ws, size_t ws_size,
                              hipStream_t stream) {
    const int*   query = (const int*)d_in[0];
    const int*   doc   = (const int*)d_in[1];
    const float* emb   = (const float*)d_in[2];
    const float* w1    = (const float*)d_in[3];
    const float* b1    = (const float*)d_in[4];
    const float* w2    = (const float*)d_in[5];
    const float* b2    = (const float*)d_in[6];
    const float* w3    = (const float*)d_in[7];
    const float* b3    = (const float*)d_in[8];
    float* outp = (float*)d_out;

    const size_t part_bytes = (size_t)B_ * SPLIT * NK_ * sizeof(float);

    if (ws_size >= part_bytes) {
        float* part = (float*)d_ws;
        knrm_bins_kernel<<<dim3(B_ * SPLIT), dim3(512), 0, stream>>>(query, doc, emb, part);
        knrm_mlp_kernel<<<dim3(B_), dim3(128), 0, stream>>>(part, w1, b1, w2, b2, w3, b3, outp);
    } else {
        knrm_kernel<<<dim3(B_), dim3(512), 0, stream>>>(query, doc, emb,
                                                        w1, b1, w2, b2, w3, b3, outp);
    }
}